// Round 2
// baseline (183.256 us; speedup 1.0000x reference)
//
#include <hip/hip_runtime.h>
#include <hip/hip_bf16.h>
#include <stdint.h>

#define N_ROWS 8192
#define DIM    1024
#define TEMP_INV 10.0f
#define NCHUNK 16
#define CHUNK_COLS 512
#define BM 128
#define BN 128
#define BK 64

typedef __attribute__((ext_vector_type(8))) short bf16x8;
typedef __attribute__((ext_vector_type(4))) float f32x4;

__device__ __forceinline__ void gload_lds16(const void* g, void* l) {
  __builtin_amdgcn_global_load_lds(
      (const __attribute__((address_space(1))) unsigned int*)g,
      (__attribute__((address_space(3))) unsigned int*)l, 16, 0, 0);
}

__device__ __forceinline__ unsigned short f2bf(float x) {
  unsigned int u = __float_as_uint(x);
  unsigned int r = (u + 0x7FFFu + ((u >> 16) & 1u)) >> 16;
  return (unsigned short)r;
}

// -------- Kernel 1: L2-normalize rows, convert to bf16 --------
__global__ void norm_bf16_kernel(const float* __restrict__ ctx,
                                 const float* __restrict__ gls,
                                 unsigned short* __restrict__ Cn,
                                 unsigned short* __restrict__ Gn) {
  int row = blockIdx.x;
  const float* src;
  unsigned short* dst;
  if (row < N_ROWS) { src = ctx + (size_t)row * DIM; dst = Cn + (size_t)row * DIM; }
  else { src = gls + (size_t)(row - N_ROWS) * DIM; dst = Gn + (size_t)(row - N_ROWS) * DIM; }
  int t = threadIdx.x;
  float4 v = ((const float4*)src)[t];
  float ss = v.x*v.x + v.y*v.y + v.z*v.z + v.w*v.w;
  #pragma unroll
  for (int m = 1; m < 64; m <<= 1) ss += __shfl_xor(ss, m);
  __shared__ float wss[4];
  if ((t & 63) == 0) wss[t >> 6] = ss;
  __syncthreads();
  float tot = wss[0] + wss[1] + wss[2] + wss[3];
  float inv = 1.0f / fmaxf(sqrtf(tot), 1e-12f);
  unsigned short o0 = f2bf(v.x * inv);
  unsigned short o1 = f2bf(v.y * inv);
  unsigned short o2 = f2bf(v.z * inv);
  unsigned short o3 = f2bf(v.w * inv);
  unsigned long long pack = (unsigned long long)o0 | ((unsigned long long)o1 << 16) |
                            ((unsigned long long)o2 << 32) | ((unsigned long long)o3 << 48);
  *(unsigned long long*)(dst + (size_t)t * 4) = pack;
}

// -------- Kernel 2: fused bf16 GEMM (C = Cn * Gn^T / T) + exp + masked row reductions --------
__global__ __launch_bounds__(256, 2)
void gemm_reduce_kernel(const unsigned short* __restrict__ Cn,
                        const unsigned short* __restrict__ Gn,
                        const int* __restrict__ labels,
                        float* __restrict__ ws_sp,
                        float* __restrict__ ws_sa,
                        float* __restrict__ ws_mx) {
  __shared__ __align__(16) unsigned short As[BM * BK];
  __shared__ __align__(16) unsigned short Bs[BN * BK];
  __shared__ float red_sa[2][BM];
  __shared__ float red_sp[2][BM];
  __shared__ float red_mx[2][BM];

  const int tid = threadIdx.x;
  const int lane = tid & 63;
  const int wv = tid >> 6;
  const int wr = wv >> 1, wc = wv & 1;
  const int row0 = blockIdx.x * BM;
  const int chunk = blockIdx.y;
  const int g = lane >> 4;        // k-group 0..3
  const int fr = lane & 15;       // fragment row/col 0..15

  // staging lane constants: region r = wv*4+i covers rows r*8..r*8+7.
  // LDS is written linearly (base + lane*16B); the XOR swizzle (slot ^= row&7)
  // is applied by pre-swizzling the GLOBAL source slot per lane.
  const int srow = lane >> 3;                 // 0..7 (row within region)
  const int scol = (lane & 7) ^ srow;         // pre-swizzled 16B slot

  // row labels for the 16 rows this lane accumulates
  int rl[16];
  #pragma unroll
  for (int m = 0; m < 4; ++m)
    #pragma unroll
    for (int j = 0; j < 4; ++j)
      rl[m*4+j] = labels[row0 + wr*64 + m*16 + g*4 + j];

  float s_all[16], s_pos[16], s_max[16];
  #pragma unroll
  for (int t = 0; t < 16; ++t) { s_all[t] = 0.f; s_pos[t] = 0.f; s_max[t] = -__builtin_inff(); }

  for (int ct = 0; ct < 4; ++ct) {
    const int col0 = chunk * CHUNK_COLS + ct * BN;
    f32x4 acc[4][4];
    #pragma unroll
    for (int m = 0; m < 4; ++m)
      #pragma unroll
      for (int n = 0; n < 4; ++n) {
        f32x4 z = {0.f, 0.f, 0.f, 0.f};
        acc[m][n] = z;
      }

    for (int kt = 0; kt < DIM / BK; ++kt) {
      const int k0 = kt * BK;
      #pragma unroll
      for (int i = 0; i < 4; ++i) {
        int r = wv * 4 + i;
        gload_lds16(Cn + (size_t)(row0 + r*8 + srow) * DIM + k0 + scol*8, &As[r * 512]);
      }
      #pragma unroll
      for (int i = 0; i < 4; ++i) {
        int r = wv * 4 + i;
        gload_lds16(Gn + (size_t)(col0 + r*8 + srow) * DIM + k0 + scol*8, &Bs[r * 512]);
      }
      __syncthreads();
      #pragma unroll
      for (int ks = 0; ks < 2; ++ks) {
        bf16x8 af[4], bfr[4];
        #pragma unroll
        for (int m = 0; m < 4; ++m) {
          int row = wr*64 + m*16 + fr;
          int u = ks*4 + g;
          af[m] = *(const bf16x8*)&As[row * BK + ((u ^ (row & 7)) << 3)];
        }
        #pragma unroll
        for (int n = 0; n < 4; ++n) {
          int row = wc*64 + n*16 + fr;
          int u = ks*4 + g;
          bfr[n] = *(const bf16x8*)&Bs[row * BK + ((u ^ (row & 7)) << 3)];
        }
        #pragma unroll
        for (int m = 0; m < 4; ++m)
          #pragma unroll
          for (int n = 0; n < 4; ++n)
            acc[m][n] = __builtin_amdgcn_mfma_f32_16x16x32_bf16(af[m], bfr[n], acc[m][n], 0, 0, 0);
      }
      __syncthreads();
    }

    // epilogue: exp + masked accumulation into per-row partials
    int cl[4], cg[4];
    #pragma unroll
    for (int n = 0; n < 4; ++n) {
      cg[n] = col0 + wc*64 + n*16 + fr;
      cl[n] = labels[cg[n]];
    }
    #pragma unroll
    for (int m = 0; m < 4; ++m) {
      #pragma unroll
      for (int j = 0; j < 4; ++j) {
        const int t = m*4 + j;
        const int rgi = row0 + wr*64 + m*16 + g*4 + j;
        #pragma unroll
        for (int n = 0; n < 4; ++n) {
          float s10 = acc[m][n][j] * TEMP_INV;
          float e = __expf(s10);
          bool offd = (rgi != cg[n]);
          float ea = offd ? e : 0.f;
          s_all[t] += ea;
          if (rl[t] == cl[n]) s_pos[t] += ea;
          s_max[t] = offd ? fmaxf(s_max[t], s10) : s_max[t];
        }
      }
    }
  }

  // reduce across the 16 lanes sharing each row (same g-group)
  #pragma unroll
  for (int t = 0; t < 16; ++t) {
    float va = s_all[t], vp = s_pos[t], vm = s_max[t];
    #pragma unroll
    for (int m = 1; m < 16; m <<= 1) {
      va += __shfl_xor(va, m);
      vp += __shfl_xor(vp, m);
      vm = fmaxf(vm, __shfl_xor(vm, m));
    }
    if (fr == 0) {
      int rloc = wr*64 + (t >> 2)*16 + g*4 + (t & 3);
      red_sa[wc][rloc] = va;
      red_sp[wc][rloc] = vp;
      red_mx[wc][rloc] = vm;
    }
  }
  __syncthreads();
  if (tid < BM) {
    size_t o = (size_t)chunk * N_ROWS + row0 + tid;
    ws_sa[o] = red_sa[0][tid] + red_sa[1][tid];
    ws_sp[o] = red_sp[0][tid] + red_sp[1][tid];
    ws_mx[o] = fmaxf(red_mx[0][tid], red_mx[1][tid]);
  }
}

// -------- Kernel 3: combine chunk partials -> per-row loss --------
__global__ void finalize_rows_kernel(const float* __restrict__ ws_sp,
                                     const float* __restrict__ ws_sa,
                                     const float* __restrict__ ws_mx,
                                     float* __restrict__ ws_loss) {
  int r = blockIdx.x * blockDim.x + threadIdx.x;
  float sp = 0.f, sa = 0.f, mx = -__builtin_inff();
  #pragma unroll
  for (int c = 0; c < NCHUNK; ++c) {
    sp += ws_sp[(size_t)c * N_ROWS + r];
    sa += ws_sa[(size_t)c * N_ROWS + r];
    mx = fmaxf(mx, ws_mx[(size_t)c * N_ROWS + r]);
  }
  float frac = (sp + 1e-8f) / (sa + 1e-8f);
  frac = fminf(fmaxf(frac, 1e-8f), 1.0f);
  float loss = -logf(frac);
  if (sp == 0.0f) loss = -mx;   // no-positives fallback (every exp term > 0)
  ws_loss[r] = loss;
}

// -------- Kernel 4: deterministic mean --------
__global__ void mean_kernel(const float* __restrict__ ws_loss, float* __restrict__ out) {
  int t = threadIdx.x;
  float s = 0.f;
  for (int i = t; i < N_ROWS; i += 256) s += ws_loss[i];
  #pragma unroll
  for (int m = 1; m < 64; m <<= 1) s += __shfl_xor(s, m);
  __shared__ float wsum[4];
  if ((t & 63) == 0) wsum[t >> 6] = s;
  __syncthreads();
  if (t == 0) out[0] = (wsum[0] + wsum[1] + wsum[2] + wsum[3]) * (1.0f / N_ROWS);
}

extern "C" void kernel_launch(void* const* d_in, const int* in_sizes, int n_in,
                              void* d_out, int out_size, void* d_ws, size_t ws_size,
                              hipStream_t stream) {
  const float* ctx = (const float*)d_in[0];
  const float* gls = (const float*)d_in[1];
  const int* labels = (const int*)d_in[2];
  float* out = (float*)d_out;

  char* ws = (char*)d_ws;
  unsigned short* Cn = (unsigned short*)ws;                                  // 16 MiB
  unsigned short* Gn = (unsigned short*)(ws + (size_t)N_ROWS * DIM * 2);     // 16 MiB
  float* ws_sp = (float*)(ws + (size_t)2 * N_ROWS * DIM * 2);
  float* ws_sa = ws_sp + (size_t)NCHUNK * N_ROWS;
  float* ws_mx = ws_sa + (size_t)NCHUNK * N_ROWS;
  float* ws_loss = ws_mx + (size_t)NCHUNK * N_ROWS;

  hipLaunchKernelGGL(norm_bf16_kernel, dim3(2 * N_ROWS), dim3(256), 0, stream,
                     ctx, gls, Cn, Gn);
  hipLaunchKernelGGL(gemm_reduce_kernel, dim3(N_ROWS / BM, NCHUNK), dim3(256), 0, stream,
                     Cn, Gn, labels, ws_sp, ws_sa, ws_mx);
  hipLaunchKernelGGL(finalize_rows_kernel, dim3(N_ROWS / 256), dim3(256), 0, stream,
                     ws_sp, ws_sa, ws_mx, ws_loss);
  hipLaunchKernelGGL(mean_kernel, dim3(1), dim3(256), 0, stream, ws_loss, out);
}